// Round 1
// baseline (657.420 us; speedup 1.0000x reference)
//
#include <hip/hip_runtime.h>

#define DHID 128

// ---------------- CSR build ----------------
__global__ void k_hist(const int* __restrict__ ei, int* __restrict__ cnt, int E) {
    int e = blockIdx.x * 256 + threadIdx.x;
    if (e < E) atomicAdd(&cnt[ei[E + e]], 1);
}

__global__ void k_dinv(const int* __restrict__ cnt, float* __restrict__ dinv, int N) {
    int i = blockIdx.x * 256 + threadIdx.x;
    if (i < N) dinv[i] = rsqrtf((float)(cnt[i] + 1));  // +1 self-loop, deg>=1 always
}

__global__ void k_reduce(const int* __restrict__ cnt, int* __restrict__ partial, int N) {
    __shared__ int s[256];
    int t = threadIdx.x;
    int i = blockIdx.x * 256 + t;
    s[t] = (i < N) ? cnt[i] : 0;
    __syncthreads();
    for (int st = 128; st > 0; st >>= 1) {
        if (t < st) s[t] += s[t + st];
        __syncthreads();
    }
    if (t == 0) partial[blockIdx.x] = s[0];
}

__global__ void k_scan_partials(const int* __restrict__ partial, int* __restrict__ blockoff, int NB) {
    __shared__ int s[1024];
    int t = threadIdx.x;
    s[t] = (t < NB) ? partial[t] : 0;
    __syncthreads();
    for (int off = 1; off < 1024; off <<= 1) {
        int v = (t >= off) ? s[t - off] : 0;
        __syncthreads();
        s[t] += v;
        __syncthreads();
    }
    if (t < NB) blockoff[t] = (t == 0) ? 0 : s[t - 1];
}

__global__ void k_scan_block(const int* __restrict__ cnt, const int* __restrict__ blockoff,
                             int* __restrict__ row_ptr, int* __restrict__ cursor, int N, int E) {
    __shared__ int s[256];
    int t = threadIdx.x;
    int i = blockIdx.x * 256 + t;
    int c = (i < N) ? cnt[i] : 0;
    s[t] = c;
    __syncthreads();
    for (int off = 1; off < 256; off <<= 1) {
        int v = (t >= off) ? s[t - off] : 0;
        __syncthreads();
        s[t] += v;
        __syncthreads();
    }
    if (i < N) {
        int rp = blockoff[blockIdx.x] + s[t] - c;  // exclusive prefix
        row_ptr[i] = rp;
        cursor[i]  = rp;
    }
    if (i == 0) row_ptr[N] = E;
}

__global__ void k_fill(const int* __restrict__ ei, int* __restrict__ cursor,
                       int* __restrict__ csr_src, int E) {
    int e = blockIdx.x * 256 + threadIdx.x;
    if (e < E) {
        int src = ei[e];
        int dst = ei[E + e];
        int pos = atomicAdd(&cursor[dst], 1);
        csr_src[pos] = src;
    }
}

// ---------------- fp32 GEMM: T[N,128] = X[N,128] @ W[128,128] ----------------
// W staged in LDS (64 KB). Block 256 threads = 64 rows x 128 cols tile.
// Thread tile: 4 rows x 8 cols.
__global__ __launch_bounds__(256) void k_gemm128(const float* __restrict__ X,
                                                 const float* __restrict__ W,
                                                 float* __restrict__ T, int N) {
    __shared__ float Ws[DHID * DHID];
    int t = threadIdx.x;
    {
        const float4* Wg4 = (const float4*)W;
        float4* Ws4 = (float4*)Ws;
#pragma unroll
        for (int i = 0; i < 16; ++i) Ws4[i * 256 + t] = Wg4[i * 256 + t];
    }
    __syncthreads();

    int tr = t >> 4;          // 0..15
    int tc = t & 15;          // 0..15
    int row0 = blockIdx.x * 64 + tr * 4;
    int col  = tc * 8;
    if (row0 >= N) return;    // no more barriers below

    int r[4];
#pragma unroll
    for (int j = 0; j < 4; ++j) {
        int rr = row0 + j;
        r[j] = (rr < N) ? rr : (N - 1);  // clamp for safe loads; stores guarded
    }

    float acc[4][8];
#pragma unroll
    for (int i = 0; i < 4; ++i)
#pragma unroll
        for (int c = 0; c < 8; ++c) acc[i][c] = 0.f;

    for (int k4 = 0; k4 < DHID; k4 += 4) {
        float4 a[4];
#pragma unroll
        for (int j = 0; j < 4; ++j)
            a[j] = *(const float4*)(X + (size_t)r[j] * DHID + k4);
#pragma unroll
        for (int j = 0; j < 4; ++j) {
            int k = k4 + j;
            float w[8];
            *(float4*)&w[0] = *(const float4*)&Ws[k * DHID + col];
            *(float4*)&w[4] = *(const float4*)&Ws[k * DHID + col + 4];
#pragma unroll
            for (int i = 0; i < 4; ++i) {
                float av = (j == 0) ? a[i].x : (j == 1) ? a[i].y : (j == 2) ? a[i].z : a[i].w;
#pragma unroll
                for (int c = 0; c < 8; ++c) acc[i][c] = fmaf(av, w[c], acc[i][c]);
            }
        }
    }

#pragma unroll
    for (int i = 0; i < 4; ++i) {
        int rr = row0 + i;
        if (rr < N) {
            float* dst = T + (size_t)rr * DHID + col;
            *(float4*)dst       = make_float4(acc[i][0], acc[i][1], acc[i][2], acc[i][3]);
            *(float4*)(dst + 4) = make_float4(acc[i][4], acc[i][5], acc[i][6], acc[i][7]);
        }
    }
}

// ---------------- aggregation: one wave per node ----------------
// out[node] = relu( dinv[node] * (sum_e dinv[src]*T[src] + dinv[node]*T[node]) + bias )
// FINAL=1 additionally fuses h2 @ Wl + bl with a wave reduce.
template <int FINAL>
__global__ __launch_bounds__(256) void k_agg(const float* __restrict__ T,
                                             const int* __restrict__ row_ptr,
                                             const int* __restrict__ csr_src,
                                             const float* __restrict__ dinv,
                                             const float* __restrict__ bias,
                                             float* __restrict__ out,
                                             const float* __restrict__ Wl,
                                             const float* __restrict__ bl, int N) {
    int node = (int)((blockIdx.x * (unsigned)blockDim.x + threadIdx.x) >> 6);
    int lane = threadIdx.x & 63;
    if (node >= N) return;

    int e = row_ptr[node];
    int end = row_ptr[node + 1];
    const float* Tl = T + (size_t)lane * 2;

    float ax = 0.f, ay = 0.f;
    int sNext = (e < end) ? csr_src[e] : 0;
    for (; e < end; ++e) {
        int s = sNext;
        sNext = (e + 1 < end) ? csr_src[e + 1] : 0;
        float w = dinv[s];
        float2 v = *(const float2*)(Tl + (size_t)s * DHID);
        ax = fmaf(w, v.x, ax);
        ay = fmaf(w, v.y, ay);
    }

    float dn = dinv[node];
    float2 tv = *(const float2*)(Tl + (size_t)node * DHID);
    ax = dn * fmaf(dn, tv.x, ax);
    ay = dn * fmaf(dn, tv.y, ay);

    float2 b = *(const float2*)(bias + lane * 2);
    float r0 = fmaxf(ax + b.x, 0.f);
    float r1 = fmaxf(ay + b.y, 0.f);

    if (FINAL == 0) {
        *(float2*)(out + (size_t)node * DHID + lane * 2) = make_float2(r0, r1);
    } else {
        float2 wl = *(const float2*)(Wl + lane * 2);
        float p = fmaf(r0, wl.x, r1 * wl.y);
#pragma unroll
        for (int off = 32; off > 0; off >>= 1) p += __shfl_down(p, off, 64);
        if (lane == 0) out[node] = p + bl[0];
    }
}

// ---------------- launch ----------------
extern "C" void kernel_launch(void* const* d_in, const int* in_sizes, int n_in,
                              void* d_out, int out_size, void* d_ws, size_t ws_size,
                              hipStream_t stream) {
    const float* x  = (const float*)d_in[0];
    const int*   ei = (const int*)d_in[1];
    const float* W1 = (const float*)d_in[2];
    const float* b1 = (const float*)d_in[3];
    const float* W2 = (const float*)d_in[4];
    const float* b2 = (const float*)d_in[5];
    const float* Wl = (const float*)d_in[6];
    const float* bl = (const float*)d_in[7];
    float* out = (float*)d_out;

    int N = in_sizes[0] / DHID;   // 100000
    int E = in_sizes[1] / 2;      // 1600000
    int NB = (N + 255) / 256;     // 391

    char* ws = (char*)d_ws;
    size_t off = 0;
    auto alloc = [&](size_t bytes) -> void* {
        void* p = ws + off;
        off += (bytes + 255) & ~(size_t)255;
        return p;
    };
    int*   cnt      = (int*)alloc((size_t)N * 4);
    float* dinv     = (float*)alloc((size_t)N * 4);
    int*   row_ptr  = (int*)alloc((size_t)(N + 1) * 4);
    int*   cursor   = (int*)alloc((size_t)N * 4);
    int*   partial  = (int*)alloc((size_t)NB * 4);
    int*   blockoff = (int*)alloc((size_t)NB * 4);
    int*   csr      = (int*)alloc((size_t)E * 4);
    float* T        = (float*)alloc((size_t)N * DHID * 4);
    float* H        = (float*)alloc((size_t)N * DHID * 4);

    // ---- build CSR + norms (once, reused by both layers) ----
    hipMemsetAsync(cnt, 0, (size_t)N * 4, stream);
    k_hist<<<(E + 255) / 256, 256, 0, stream>>>(ei, cnt, E);
    k_dinv<<<NB, 256, 0, stream>>>(cnt, dinv, N);
    k_reduce<<<NB, 256, 0, stream>>>(cnt, partial, N);
    k_scan_partials<<<1, 1024, 0, stream>>>(partial, blockoff, NB);
    k_scan_block<<<NB, 256, 0, stream>>>(cnt, blockoff, row_ptr, cursor, N, E);
    k_fill<<<(E + 255) / 256, 256, 0, stream>>>(ei, cursor, csr, E);

    // ---- layer 1 ----
    k_gemm128<<<(N + 63) / 64, 256, 0, stream>>>(x, W1, T, N);
    k_agg<0><<<(N + 3) / 4, 256, 0, stream>>>(T, row_ptr, csr, dinv, b1, H, nullptr, nullptr, N);

    // ---- layer 2 + fused final projection ----
    k_gemm128<<<(N + 63) / 64, 256, 0, stream>>>(H, W2, T, N);
    k_agg<1><<<(N + 3) / 4, 256, 0, stream>>>(T, row_ptr, csr, dinv, b2, out, Wl, bl, N);
}

// Round 3
// 469.391 us; speedup vs baseline: 1.4006x; 1.4006x over previous
//
#include <hip/hip_runtime.h>

#define DHID 128

typedef _Float16 h2 __attribute__((ext_vector_type(2)));
typedef _Float16 h8 __attribute__((ext_vector_type(8)));
typedef float    f2 __attribute__((ext_vector_type(2)));

// ---------------- CSR build ----------------
__global__ void k_hist(const int* __restrict__ ei, int* __restrict__ cnt, int E) {
    int e = blockIdx.x * 256 + threadIdx.x;
    if (e < E) atomicAdd(&cnt[ei[E + e]], 1);
}

__global__ void k_dinv(const int* __restrict__ cnt, float* __restrict__ dinv, int N) {
    int i = blockIdx.x * 256 + threadIdx.x;
    if (i < N) dinv[i] = rsqrtf((float)(cnt[i] + 1));  // +1 self-loop, deg>=1 always
}

__global__ void k_reduce(const int* __restrict__ cnt, int* __restrict__ partial, int N) {
    __shared__ int s[256];
    int t = threadIdx.x;
    int i = blockIdx.x * 256 + t;
    s[t] = (i < N) ? cnt[i] : 0;
    __syncthreads();
    for (int st = 128; st > 0; st >>= 1) {
        if (t < st) s[t] += s[t + st];
        __syncthreads();
    }
    if (t == 0) partial[blockIdx.x] = s[0];
}

__global__ void k_scan_partials(const int* __restrict__ partial, int* __restrict__ blockoff, int NB) {
    __shared__ int s[1024];
    int t = threadIdx.x;
    s[t] = (t < NB) ? partial[t] : 0;
    __syncthreads();
    for (int off = 1; off < 1024; off <<= 1) {
        int v = (t >= off) ? s[t - off] : 0;
        __syncthreads();
        s[t] += v;
        __syncthreads();
    }
    if (t < NB) blockoff[t] = (t == 0) ? 0 : s[t - 1];
}

__global__ void k_scan_block(const int* __restrict__ cnt, const int* __restrict__ blockoff,
                             int* __restrict__ row_ptr, int* __restrict__ cursor, int N, int E) {
    __shared__ int s[256];
    int t = threadIdx.x;
    int i = blockIdx.x * 256 + t;
    int c = (i < N) ? cnt[i] : 0;
    s[t] = c;
    __syncthreads();
    for (int off = 1; off < 256; off <<= 1) {
        int v = (t >= off) ? s[t - off] : 0;
        __syncthreads();
        s[t] += v;
        __syncthreads();
    }
    if (i < N) {
        int rp = blockoff[blockIdx.x] + s[t] - c;  // exclusive prefix
        row_ptr[i] = rp;
        cursor[i]  = rp;
    }
    if (i == 0) row_ptr[N] = E;
}

__global__ void k_fill(const int* __restrict__ ei, int* __restrict__ cursor,
                       int* __restrict__ csr_src, int E) {
    int e = blockIdx.x * 256 + threadIdx.x;
    if (e < E) {
        int src = ei[e];
        int dst = ei[E + e];
        int pos = atomicAdd(&cursor[dst], 1);
        csr_src[pos] = src;
    }
}

// ---------------- fp32 GEMM: Th[N,128] = fp16( dinv[row] * (X[N,128] @ W[128,128]) ) --
// W staged in LDS (64 KB). Block 256 threads = 64 rows x 128 cols tile.
// Thread tile: 4 rows x 8 cols. Epilogue pre-scales by dinv[row] and packs fp16.
__global__ __launch_bounds__(256) void k_gemm128(const float* __restrict__ X,
                                                 const float* __restrict__ W,
                                                 const float* __restrict__ dinv,
                                                 _Float16* __restrict__ Th, int N) {
    __shared__ float Ws[DHID * DHID];
    int t = threadIdx.x;
    {
        const float4* Wg4 = (const float4*)W;
        float4* Ws4 = (float4*)Ws;
#pragma unroll
        for (int i = 0; i < 16; ++i) Ws4[i * 256 + t] = Wg4[i * 256 + t];
    }
    __syncthreads();

    int tr = t >> 4;          // 0..15
    int tc = t & 15;          // 0..15
    int row0 = blockIdx.x * 64 + tr * 4;
    int col  = tc * 8;
    if (row0 >= N) return;    // no more barriers below

    int r[4];
#pragma unroll
    for (int j = 0; j < 4; ++j) {
        int rr = row0 + j;
        r[j] = (rr < N) ? rr : (N - 1);  // clamp for safe loads; stores guarded
    }

    float acc[4][8];
#pragma unroll
    for (int i = 0; i < 4; ++i)
#pragma unroll
        for (int c = 0; c < 8; ++c) acc[i][c] = 0.f;

    for (int k4 = 0; k4 < DHID; k4 += 4) {
        float4 a[4];
#pragma unroll
        for (int j = 0; j < 4; ++j)
            a[j] = *(const float4*)(X + (size_t)r[j] * DHID + k4);
#pragma unroll
        for (int j = 0; j < 4; ++j) {
            int k = k4 + j;
            float w[8];
            *(float4*)&w[0] = *(const float4*)&Ws[k * DHID + col];
            *(float4*)&w[4] = *(const float4*)&Ws[k * DHID + col + 4];
#pragma unroll
            for (int i = 0; i < 4; ++i) {
                float av = (j == 0) ? a[i].x : (j == 1) ? a[i].y : (j == 2) ? a[i].z : a[i].w;
#pragma unroll
                for (int c = 0; c < 8; ++c) acc[i][c] = fmaf(av, w[c], acc[i][c]);
            }
        }
    }

#pragma unroll
    for (int i = 0; i < 4; ++i) {
        int rr = row0 + i;
        if (rr < N) {
            float s = dinv[rr];
            h8 v;
#pragma unroll
            for (int c = 0; c < 8; ++c) v[c] = (_Float16)(acc[i][c] * s);
            *(h8*)(Th + (size_t)rr * DHID + col) = v;
        }
    }
}

// ---------------- aggregation: one wave per node ----------------
// Th rows are pre-scaled by dinv[src]:  Th[i] = fp16(dinv[i] * (X@W)[i]).
// out[node] = relu( dinv[node] * (Σ_src Th[src] + Th[node]) + bias )
// FINAL=1 additionally fuses h2 @ Wl + bl with a wave reduce.
template <int FINAL>
__global__ __launch_bounds__(256) void k_agg(const _Float16* __restrict__ Th,
                                             const int* __restrict__ row_ptr,
                                             const int* __restrict__ csr_src,
                                             const float* __restrict__ dinv,
                                             const float* __restrict__ bias,
                                             float* __restrict__ out,
                                             const float* __restrict__ Wl,
                                             const float* __restrict__ bl, int N) {
    int node = (int)((blockIdx.x * (unsigned)blockDim.x + threadIdx.x) >> 6);
    int lane = threadIdx.x & 63;
    if (node >= N) return;

    int e = row_ptr[node];
    int end = row_ptr[node + 1];
    const h2* Tl = (const h2*)Th + lane;   // lane's 2 columns; row r at Tl[r*64]

    float ax = 0.f, ay = 0.f;
    // 4x unrolled: 4 independent row gathers in flight
    for (; e + 4 <= end; e += 4) {
        int s0 = csr_src[e];
        int s1 = csr_src[e + 1];
        int s2 = csr_src[e + 2];
        int s3 = csr_src[e + 3];
        h2 v0 = Tl[(size_t)s0 * 64];
        h2 v1 = Tl[(size_t)s1 * 64];
        h2 v2 = Tl[(size_t)s2 * 64];
        h2 v3 = Tl[(size_t)s3 * 64];
        ax += (float)v0.x + (float)v1.x + (float)v2.x + (float)v3.x;
        ay += (float)v0.y + (float)v1.y + (float)v2.y + (float)v3.y;
    }
    for (; e < end; ++e) {
        int s = csr_src[e];
        h2 v = Tl[(size_t)s * 64];
        ax += (float)v.x;
        ay += (float)v.y;
    }

    // self-loop term (Th already dinv-scaled), then outer dinv[node] scale
    {
        h2 tv = Tl[(size_t)node * 64];
        ax += (float)tv.x;
        ay += (float)tv.y;
    }
    float dn = dinv[node];
    float2 b = *(const float2*)(bias + lane * 2);
    float r0 = fmaxf(fmaf(dn, ax, b.x), 0.f);
    float r1 = fmaxf(fmaf(dn, ay, b.y), 0.f);

    if (FINAL == 0) {
        f2 v; v.x = r0; v.y = r1;
        __builtin_nontemporal_store(v, (f2*)(out + (size_t)node * DHID + lane * 2));
    } else {
        float2 wl = *(const float2*)(Wl + lane * 2);
        float p = fmaf(r0, wl.x, r1 * wl.y);
#pragma unroll
        for (int off = 32; off > 0; off >>= 1) p += __shfl_down(p, off, 64);
        if (lane == 0) out[node] = p + bl[0];
    }
}

// ---------------- launch ----------------
extern "C" void kernel_launch(void* const* d_in, const int* in_sizes, int n_in,
                              void* d_out, int out_size, void* d_ws, size_t ws_size,
                              hipStream_t stream) {
    const float* x  = (const float*)d_in[0];
    const int*   ei = (const int*)d_in[1];
    const float* W1 = (const float*)d_in[2];
    const float* b1 = (const float*)d_in[3];
    const float* W2 = (const float*)d_in[4];
    const float* b2 = (const float*)d_in[5];
    const float* Wl = (const float*)d_in[6];
    const float* bl = (const float*)d_in[7];
    float* out = (float*)d_out;

    int N = in_sizes[0] / DHID;   // 100000
    int E = in_sizes[1] / 2;      // 1600000
    int NB = (N + 255) / 256;     // 391

    char* ws = (char*)d_ws;
    size_t off = 0;
    auto alloc = [&](size_t bytes) -> void* {
        void* p = ws + off;
        off += (bytes + 255) & ~(size_t)255;
        return p;
    };
    int*      cnt      = (int*)alloc((size_t)N * 4);
    float*    dinv     = (float*)alloc((size_t)N * 4);
    int*      row_ptr  = (int*)alloc((size_t)(N + 1) * 4);
    int*      cursor   = (int*)alloc((size_t)N * 4);
    int*      partial  = (int*)alloc((size_t)NB * 4);
    int*      blockoff = (int*)alloc((size_t)NB * 4);
    int*      csr      = (int*)alloc((size_t)E * 4);
    _Float16* Th       = (_Float16*)alloc((size_t)N * DHID * 2);
    float*    H        = (float*)alloc((size_t)N * DHID * 4);

    // ---- build CSR + norms (once, reused by both layers) ----
    (void)hipMemsetAsync(cnt, 0, (size_t)N * 4, stream);
    k_hist<<<(E + 255) / 256, 256, 0, stream>>>(ei, cnt, E);
    k_dinv<<<NB, 256, 0, stream>>>(cnt, dinv, N);
    k_reduce<<<NB, 256, 0, stream>>>(cnt, partial, N);
    k_scan_partials<<<1, 1024, 0, stream>>>(partial, blockoff, NB);
    k_scan_block<<<NB, 256, 0, stream>>>(cnt, blockoff, row_ptr, cursor, N, E);
    k_fill<<<(E + 255) / 256, 256, 0, stream>>>(ei, cursor, csr, E);

    // ---- layer 1 ----
    k_gemm128<<<(N + 63) / 64, 256, 0, stream>>>(x, W1, dinv, Th, N);
    k_agg<0><<<(N + 3) / 4, 256, 0, stream>>>(Th, row_ptr, csr, dinv, b1, H, nullptr, nullptr, N);

    // ---- layer 2 + fused final projection ----
    k_gemm128<<<(N + 63) / 64, 256, 0, stream>>>(H, W2, dinv, Th, N);
    k_agg<1><<<(N + 3) / 4, 256, 0, stream>>>(Th, row_ptr, csr, dinv, b2, out, Wl, bl, N);
}

// Round 4
// 306.349 us; speedup vs baseline: 2.1460x; 1.5322x over previous
//
#include <hip/hip_runtime.h>

#define DHID 128
#define NBUCK_MAX 256      // buckets of 512 nodes each; N=100000 -> 196 buckets
#define BCAP 10240         // per-bucket capacity (mean 8163, std ~90 -> 23 sigma)
#define PCHUNK 4096        // edges per partition block

typedef _Float16 h8 __attribute__((ext_vector_type(8)));
typedef float    f2 __attribute__((ext_vector_type(2)));

// ---------------- phase 1: partition edges into 512-node buckets ----------------
// packed entry: (dst & 511) << 17 | src   (src < 2^17)
__global__ __launch_bounds__(256) void k_partition(const int* __restrict__ ei, int E, int nbuck,
                                                   int* __restrict__ bucket_cursor,
                                                   unsigned* __restrict__ packed) {
    __shared__ unsigned sdata[PCHUNK];
    __shared__ int lcnt[256], lbase[256], loff[256], lcur[256], sscan[256];
    int t = threadIdx.x;
    int e0 = blockIdx.x * PCHUNK;
    lcnt[t] = 0;
    __syncthreads();

    // pass A: count per bucket
    for (int i = t; i < PCHUNK; i += 256) {
        int e = e0 + i;
        if (e < E) {
            int d = ei[E + e];
            atomicAdd(&lcnt[d >> 9], 1);
        }
    }
    __syncthreads();

    // exclusive scan of lcnt -> loff (LDS segment layout), reserve global space
    int c = lcnt[t];
    sscan[t] = c;
    __syncthreads();
    for (int off = 1; off < 256; off <<= 1) {
        int v = (t >= off) ? sscan[t - off] : 0;
        __syncthreads();
        sscan[t] += v;
        __syncthreads();
    }
    loff[t] = sscan[t] - c;
    if (t < nbuck && c > 0) lbase[t] = atomicAdd(&bucket_cursor[t], c);
    lcur[t] = sscan[t] - c;
    __syncthreads();

    // pass B: scatter packed entries into LDS, grouped by bucket
    for (int i = t; i < PCHUNK; i += 256) {
        int e = e0 + i;
        if (e < E) {
            int s = ei[e];
            int d = ei[E + e];
            int b = d >> 9;
            int pos = atomicAdd(&lcur[b], 1);
            sdata[pos] = ((unsigned)(d & 511) << 17) | (unsigned)s;
        }
    }
    __syncthreads();

    // pass C: one wave per bucket, copy contiguous LDS segment to global bucket region
    int wid = t >> 6, lane = t & 63;
    for (int b = wid; b < nbuck; b += 4) {
        int cb = lcnt[b];
        if (cb == 0) continue;
        int gbase = b * BCAP + lbase[b];
        int sbase = loff[b];
        for (int k = lane; k < cb; k += 64) packed[gbase + k] = sdata[sbase + k];
    }
}

// ---------------- phase 2a: per-node degree from bucketed data ----------------
__global__ __launch_bounds__(256) void k_p2a(const unsigned* __restrict__ packed,
                                             const int* __restrict__ bucket_cursor,
                                             int* __restrict__ cnt, int N) {
    __shared__ int c512[512];
    int t = threadIdx.x, b = blockIdx.x;
    c512[t] = 0; c512[t + 256] = 0;
    __syncthreads();
    int m = bucket_cursor[b];
    const unsigned* pb = packed + (size_t)b * BCAP;
    for (int i = t; i < m; i += 256) atomicAdd(&c512[pb[i] >> 17], 1);
    __syncthreads();
    int base = b << 9;
#pragma unroll
    for (int j = 0; j < 2; ++j) {
        int node = base + t + j * 256;
        if (node < N) cnt[node] = c512[t + j * 256];
    }
}

__global__ void k_dinv(const int* __restrict__ cnt, float* __restrict__ dinv, int N) {
    int i = blockIdx.x * 256 + threadIdx.x;
    if (i < N) dinv[i] = rsqrtf((float)(cnt[i] + 1));  // +1 self-loop
}

__global__ void k_reduce(const int* __restrict__ cnt, int* __restrict__ partial, int N) {
    __shared__ int s[256];
    int t = threadIdx.x;
    int i = blockIdx.x * 256 + t;
    s[t] = (i < N) ? cnt[i] : 0;
    __syncthreads();
    for (int st = 128; st > 0; st >>= 1) {
        if (t < st) s[t] += s[t + st];
        __syncthreads();
    }
    if (t == 0) partial[blockIdx.x] = s[0];
}

__global__ void k_scan_partials(const int* __restrict__ partial, int* __restrict__ blockoff, int NB) {
    __shared__ int s[1024];
    int t = threadIdx.x;
    s[t] = (t < NB) ? partial[t] : 0;
    __syncthreads();
    for (int off = 1; off < 1024; off <<= 1) {
        int v = (t >= off) ? s[t - off] : 0;
        __syncthreads();
        s[t] += v;
        __syncthreads();
    }
    if (t < NB) blockoff[t] = (t == 0) ? 0 : s[t - 1];
}

__global__ void k_scan_block(const int* __restrict__ cnt, const int* __restrict__ blockoff,
                             int* __restrict__ row_ptr, int N, int E) {
    __shared__ int s[256];
    int t = threadIdx.x;
    int i = blockIdx.x * 256 + t;
    int c = (i < N) ? cnt[i] : 0;
    s[t] = c;
    __syncthreads();
    for (int off = 1; off < 256; off <<= 1) {
        int v = (t >= off) ? s[t - off] : 0;
        __syncthreads();
        s[t] += v;
        __syncthreads();
    }
    if (i < N) row_ptr[i] = blockoff[blockIdx.x] + s[t] - c;
    if (i == 0) row_ptr[N] = E;
}

// ---------------- phase 2b: in-bucket counting sort -> csr ----------------
// Random writes confined to this block's own ~32KB csr segment (L2-resident).
__global__ __launch_bounds__(256) void k_p2b(const unsigned* __restrict__ packed,
                                             const int* __restrict__ bucket_cursor,
                                             const int* __restrict__ row_ptr,
                                             int* __restrict__ csr, int N) {
    __shared__ int c512[512], cur512[512], sscan[256];
    int t = threadIdx.x, b = blockIdx.x;
    c512[t] = 0; c512[t + 256] = 0;
    __syncthreads();
    int m = bucket_cursor[b];
    const unsigned* pb = packed + (size_t)b * BCAP;
    for (int i = t; i < m; i += 256) atomicAdd(&c512[pb[i] >> 17], 1);
    __syncthreads();
    // exclusive scan over 512: pair-reduce then 256-ladder
    int v0 = c512[2 * t], v1 = c512[2 * t + 1];
    int ps = v0 + v1;
    sscan[t] = ps;
    __syncthreads();
    for (int off = 1; off < 256; off <<= 1) {
        int v = (t >= off) ? sscan[t - off] : 0;
        __syncthreads();
        sscan[t] += v;
        __syncthreads();
    }
    int excl = sscan[t] - ps;
    cur512[2 * t] = excl;
    cur512[2 * t + 1] = excl + v0;
    __syncthreads();
    int rbase = row_ptr[b << 9];
    for (int i = t; i < m; i += 256) {
        unsigned p = pb[i];
        int dl = p >> 17;
        int src = (int)(p & 0x1FFFFu);
        int pos = atomicAdd(&cur512[dl], 1);
        csr[rbase + pos] = src;
    }
}

// ---------------- fp32 GEMM: Th[N,128] = fp16( dinv[row] * (X @ W) ) ----------------
typedef _Float16 h8_t __attribute__((ext_vector_type(8)));
__global__ __launch_bounds__(256) void k_gemm128(const float* __restrict__ X,
                                                 const float* __restrict__ W,
                                                 const float* __restrict__ dinv,
                                                 _Float16* __restrict__ Th, int N) {
    __shared__ float Ws[DHID * DHID];
    int t = threadIdx.x;
    {
        const float4* Wg4 = (const float4*)W;
        float4* Ws4 = (float4*)Ws;
#pragma unroll
        for (int i = 0; i < 16; ++i) Ws4[i * 256 + t] = Wg4[i * 256 + t];
    }
    __syncthreads();

    int tr = t >> 4;
    int tc = t & 15;
    int row0 = blockIdx.x * 64 + tr * 4;
    int col  = tc * 8;
    if (row0 >= N) return;

    int r[4];
#pragma unroll
    for (int j = 0; j < 4; ++j) {
        int rr = row0 + j;
        r[j] = (rr < N) ? rr : (N - 1);
    }

    float acc[4][8];
#pragma unroll
    for (int i = 0; i < 4; ++i)
#pragma unroll
        for (int c = 0; c < 8; ++c) acc[i][c] = 0.f;

    for (int k4 = 0; k4 < DHID; k4 += 4) {
        float4 a[4];
#pragma unroll
        for (int j = 0; j < 4; ++j)
            a[j] = *(const float4*)(X + (size_t)r[j] * DHID + k4);
#pragma unroll
        for (int j = 0; j < 4; ++j) {
            int k = k4 + j;
            float w[8];
            *(float4*)&w[0] = *(const float4*)&Ws[k * DHID + col];
            *(float4*)&w[4] = *(const float4*)&Ws[k * DHID + col + 4];
#pragma unroll
            for (int i = 0; i < 4; ++i) {
                float av = (j == 0) ? a[i].x : (j == 1) ? a[i].y : (j == 2) ? a[i].z : a[i].w;
#pragma unroll
                for (int c = 0; c < 8; ++c) acc[i][c] = fmaf(av, w[c], acc[i][c]);
            }
        }
    }

#pragma unroll
    for (int i = 0; i < 4; ++i) {
        int rr = row0 + i;
        if (rr < N) {
            float s = dinv[rr];
            h8_t v;
#pragma unroll
            for (int c = 0; c < 8; ++c) v[c] = (_Float16)(acc[i][c] * s);
            *(h8_t*)(Th + (size_t)rr * DHID + col) = v;
        }
    }
}

// ---------------- aggregation: 4 nodes per wave, 16 lanes x h8 per node ----------------
// Th rows pre-scaled by dinv[src].  out = relu(dinv[node]*(sum Th[src] + Th[node]) + b)
template <int FINAL>
__global__ __launch_bounds__(256) void k_agg(const _Float16* __restrict__ Th,
                                             const int* __restrict__ row_ptr,
                                             const int* __restrict__ csr_src,
                                             const float* __restrict__ dinv,
                                             const float* __restrict__ bias,
                                             float* __restrict__ out,
                                             const float* __restrict__ Wl,
                                             const float* __restrict__ bl, int N) {
    int node = blockIdx.x * 16 + (threadIdx.x >> 4);   // 16 nodes per 256-thread block
    int sl = threadIdx.x & 15;                         // lane within node's 16-lane group
    if (node >= N) return;

    int e = row_ptr[node];
    int end = row_ptr[node + 1];
    const h8* Tl = (const h8*)Th + sl;                 // row r at Tl[r*16]; 16B per lane

    float acc[8];
#pragma unroll
    for (int c = 0; c < 8; ++c) acc[c] = 0.f;

    // 2-deep pipeline: 2 gathers in flight per subgroup, x4 subgroups per wave
    for (; e + 2 <= end; e += 2) {
        int s0 = csr_src[e];
        int s1 = csr_src[e + 1];
        h8 va = Tl[(size_t)s0 * 16];
        h8 vb = Tl[(size_t)s1 * 16];
#pragma unroll
        for (int c = 0; c < 8; ++c) acc[c] += (float)va[c] + (float)vb[c];
    }
    if (e < end) {
        int s0 = csr_src[e];
        h8 va = Tl[(size_t)s0 * 16];
#pragma unroll
        for (int c = 0; c < 8; ++c) acc[c] += (float)va[c];
    }

    // self-loop (Th already dinv-scaled)
    {
        h8 tv = Tl[(size_t)node * 16];
#pragma unroll
        for (int c = 0; c < 8; ++c) acc[c] += (float)tv[c];
    }

    float dn = dinv[node];
    const float* bp = bias + sl * 8;
    float4 b0 = *(const float4*)bp;
    float4 b1 = *(const float4*)(bp + 4);
    float r[8];
    r[0] = fmaxf(fmaf(dn, acc[0], b0.x), 0.f);
    r[1] = fmaxf(fmaf(dn, acc[1], b0.y), 0.f);
    r[2] = fmaxf(fmaf(dn, acc[2], b0.z), 0.f);
    r[3] = fmaxf(fmaf(dn, acc[3], b0.w), 0.f);
    r[4] = fmaxf(fmaf(dn, acc[4], b1.x), 0.f);
    r[5] = fmaxf(fmaf(dn, acc[5], b1.y), 0.f);
    r[6] = fmaxf(fmaf(dn, acc[6], b1.z), 0.f);
    r[7] = fmaxf(fmaf(dn, acc[7], b1.w), 0.f);

    if (FINAL == 0) {
        float* dst = out + (size_t)node * DHID + sl * 8;
        *(float4*)dst       = make_float4(r[0], r[1], r[2], r[3]);
        *(float4*)(dst + 4) = make_float4(r[4], r[5], r[6], r[7]);
    } else {
        const float* wp = Wl + sl * 8;
        float4 w0 = *(const float4*)wp;
        float4 w1 = *(const float4*)(wp + 4);
        float p = r[0] * w0.x + r[1] * w0.y + r[2] * w0.z + r[3] * w0.w +
                  r[4] * w1.x + r[5] * w1.y + r[6] * w1.z + r[7] * w1.w;
#pragma unroll
        for (int off = 8; off > 0; off >>= 1) p += __shfl_down(p, off, 16);
        if (sl == 0) out[node] = p + bl[0];
    }
}

// ---------------- launch ----------------
extern "C" void kernel_launch(void* const* d_in, const int* in_sizes, int n_in,
                              void* d_out, int out_size, void* d_ws, size_t ws_size,
                              hipStream_t stream) {
    const float* x  = (const float*)d_in[0];
    const int*   ei = (const int*)d_in[1];
    const float* W1 = (const float*)d_in[2];
    const float* b1 = (const float*)d_in[3];
    const float* W2 = (const float*)d_in[4];
    const float* b2 = (const float*)d_in[5];
    const float* Wl = (const float*)d_in[6];
    const float* bl = (const float*)d_in[7];
    float* out = (float*)d_out;

    int N = in_sizes[0] / DHID;     // 100000
    int E = in_sizes[1] / 2;        // 1600000
    int NB = (N + 255) / 256;       // 391
    int nbuck = (N + 511) / 512;    // 196

    char* ws = (char*)d_ws;
    size_t off = 0;
    auto alloc = [&](size_t bytes) -> void* {
        void* p = ws + off;
        off += (bytes + 255) & ~(size_t)255;
        return p;
    };
    int*      cnt      = (int*)alloc((size_t)N * 4);
    float*    dinv     = (float*)alloc((size_t)N * 4);
    int*      row_ptr  = (int*)alloc((size_t)(N + 1) * 4);
    int*      partial  = (int*)alloc((size_t)NB * 4);
    int*      blockoff = (int*)alloc((size_t)NB * 4);
    int*      bcur     = (int*)alloc((size_t)nbuck * 4);
    int*      csr      = (int*)alloc((size_t)E * 4);
    unsigned* packed   = (unsigned*)alloc((size_t)nbuck * BCAP * 4);
    _Float16* Th       = (_Float16*)alloc((size_t)N * DHID * 2);
    float*    H        = (float*)alloc((size_t)N * DHID * 4);

    // ---- CSR build (bucketed counting sort; reused by both layers) ----
    (void)hipMemsetAsync(bcur, 0, (size_t)nbuck * 4, stream);
    k_partition<<<(E + PCHUNK - 1) / PCHUNK, 256, 0, stream>>>(ei, E, nbuck, bcur, packed);
    k_p2a<<<nbuck, 256, 0, stream>>>(packed, bcur, cnt, N);
    k_dinv<<<NB, 256, 0, stream>>>(cnt, dinv, N);
    k_reduce<<<NB, 256, 0, stream>>>(cnt, partial, N);
    k_scan_partials<<<1, 1024, 0, stream>>>(partial, blockoff, NB);
    k_scan_block<<<NB, 256, 0, stream>>>(cnt, blockoff, row_ptr, N, E);
    k_p2b<<<nbuck, 256, 0, stream>>>(packed, bcur, row_ptr, csr, N);

    // ---- layer 1 ----
    k_gemm128<<<(N + 63) / 64, 256, 0, stream>>>(x, W1, dinv, Th, N);
    k_agg<0><<<(N + 15) / 16, 256, 0, stream>>>(Th, row_ptr, csr, dinv, b1, H, nullptr, nullptr, N);

    // ---- layer 2 + fused final projection ----
    k_gemm128<<<(N + 63) / 64, 256, 0, stream>>>(H, W2, dinv, Th, N);
    k_agg<1><<<(N + 15) / 16, 256, 0, stream>>>(Th, row_ptr, csr, dinv, b2, out, Wl, bl, N);
}